// Round 12
// baseline (881.765 us; speedup 1.0000x reference)
//
#include <hip/hip_runtime.h>
#include <hip/hip_fp16.h>
#include <hip/hip_bf16.h>

// ---------------- small helpers ----------------
__device__ __forceinline__ float4 f4_fma(float4 a, float s, float4 acc) {
    acc.x = fmaf(a.x, s, acc.x); acc.y = fmaf(a.y, s, acc.y);
    acc.z = fmaf(a.z, s, acc.z); acc.w = fmaf(a.w, s, acc.w);
    return acc;
}

typedef const __attribute__((address_space(1))) unsigned int* gas_u32;
typedef __attribute__((address_space(3))) unsigned int* las_u32;

__device__ __forceinline__ void gl_lds16(const float* g, float* l) {
    __builtin_amdgcn_global_load_lds((gas_u32)(const void*)g, (las_u32)(void*)l, 16, 0, 0);
}

// f32x4 -> f16x4 packed store (8 B)
__device__ __forceinline__ void store_half4(__half* p, float4 v) {
    union { __half2 h[2]; uint2 u; } pk;
    pk.h[0] = __floats2half2_rn(v.x, v.y);
    pk.h[1] = __floats2half2_rn(v.z, v.w);
    *(uint2*)p = pk.u;
}

// accumulate 8 halves (one uint4) into 8 f32 accumulators
__device__ __forceinline__ void acc_half8(float* acc, uint4 raw) {
    union { uint4 u; __half2 h[4]; } pk; pk.u = raw;
    float2 f0 = __half22float2(pk.h[0]);
    float2 f1 = __half22float2(pk.h[1]);
    float2 f2 = __half22float2(pk.h[2]);
    float2 f3 = __half22float2(pk.h[3]);
    acc[0] += f0.x; acc[1] += f0.y; acc[2] += f1.x; acc[3] += f1.y;
    acc[4] += f2.x; acc[5] += f2.y; acc[6] += f3.x; acc[7] += f3.y;
}

#define BSHIFT 7   // 128 nodes per bucket

// ---------------- degree count ----------------
__global__ __launch_bounds__(256) void cnt_count4_kernel(const int4* __restrict__ dst4, int* cnt, int E4) {
    int i = blockIdx.x * blockDim.x + threadIdx.x;
    if (i < E4) {
        int4 d = dst4[i];
        atomicAdd(&cnt[d.x], 1);
        atomicAdd(&cnt[d.y], 1);
        atomicAdd(&cnt[d.z], 1);
        atomicAdd(&cnt[d.w], 1);
    }
}
__global__ __launch_bounds__(256) void cnt_count_kernel(const int* __restrict__ dst, int* cnt, int E) {
    int i = blockIdx.x * blockDim.x + threadIdx.x;
    if (i < E) atomicAdd(&cnt[dst[i]], 1);
}

// ---------------- exclusive scan (N ~ 100k) ----------------
#define SCAN_CHUNK 4096  // 256 threads * 16

__global__ __launch_bounds__(256) void scan_reduce_kernel(const int* __restrict__ cnt, int* bsum, int N) {
    __shared__ int sdata[256];
    int base = blockIdx.x * SCAN_CHUNK;
    int s = 0;
    for (int k = 0; k < 16; ++k) {
        int i = base + k * 256 + threadIdx.x;
        if (i < N) s += cnt[i];
    }
    sdata[threadIdx.x] = s;
    __syncthreads();
    for (int off = 128; off > 0; off >>= 1) {
        if (threadIdx.x < off) sdata[threadIdx.x] += sdata[threadIdx.x + off];
        __syncthreads();
    }
    if (threadIdx.x == 0) bsum[blockIdx.x] = sdata[0];
}

__global__ void scan_bsum_kernel(int* bsum, int B, int* rowptr_end, int E) {
    if (threadIdx.x == 0 && blockIdx.x == 0) {
        int run = 0;
        for (int i = 0; i < B; ++i) { int v = bsum[i]; bsum[i] = run; run += v; }
        *rowptr_end = E;  // rowptr[N] = E
    }
}

// emits rowptr, cursor (=rowptr copy), dinv, and per-bucket cursor bcur (=rowptr at node b*128)
__global__ __launch_bounds__(256) void scan_write_kernel(const int* __restrict__ cnt,
                                                         const int* __restrict__ bsum,
                                                         int* rowptr, int* cursor,
                                                         float* dinv, int* bcur, int N) {
    __shared__ int sdata[256];
    int base = blockIdx.x * SCAN_CHUNK;
    int tbase = base + threadIdx.x * 16;
    int loc[16];
    int s = 0;
    for (int k = 0; k < 16; ++k) {
        int i = tbase + k;
        int v = (i < N) ? cnt[i] : 0;
        loc[k] = s; s += v;
    }
    sdata[threadIdx.x] = s;
    __syncthreads();
    for (int off = 1; off < 256; off <<= 1) {
        int v = sdata[threadIdx.x];
        int add = (threadIdx.x >= off) ? sdata[threadIdx.x - off] : 0;
        __syncthreads();
        sdata[threadIdx.x] = v + add;
        __syncthreads();
    }
    int texcl = (threadIdx.x == 0) ? 0 : sdata[threadIdx.x - 1];
    int boff = bsum[blockIdx.x];
    for (int k = 0; k < 16; ++k) {
        int i = tbase + k;
        if (i < N) {
            int rp = boff + texcl + loc[k];
            rowptr[i] = rp;
            cursor[i] = rp;
            dinv[i] = rsqrtf((float)(cnt[i] + 1));
            if ((i & ((1 << BSHIFT) - 1)) == 0) bcur[i >> BSHIFT] = rp;
        }
    }
}

// ---------------- binned two-pass csr fill ----------------
// Pass A: append (src,dst) to per-bucket staging region (bucket = dst>>7).
// Appends to a bucket are concurrent across the grid -> staging lines fill
// within ~us -> full-line writebacks (vs 16x partial-line amplification of
// direct fill: R9 PMC 107MB writeback for 6.4MB data).
__global__ __launch_bounds__(256) void bin4_kernel(const int4* __restrict__ src4,
                                                   const int4* __restrict__ dst4,
                                                   int* bcur, int2* __restrict__ stg,
                                                   int E4) {
    int i = blockIdx.x * blockDim.x + threadIdx.x;
    if (i >= E4) return;
    int4 s = src4[i];
    int4 d = dst4[i];
    int p0 = atomicAdd(&bcur[d.x >> BSHIFT], 1);
    int p1 = atomicAdd(&bcur[d.y >> BSHIFT], 1);
    int p2 = atomicAdd(&bcur[d.z >> BSHIFT], 1);
    int p3 = atomicAdd(&bcur[d.w >> BSHIFT], 1);
    stg[p0] = make_int2(s.x, d.x);
    stg[p1] = make_int2(s.y, d.y);
    stg[p2] = make_int2(s.z, d.z);
    stg[p3] = make_int2(s.w, d.w);
}

// Pass B: linear read of staging; writes to col land in the bucket's ~6KB
// window over a short interval -> lines assemble fully in L2.
__global__ __launch_bounds__(256) void fillB4_kernel(const int4* __restrict__ stg2,
                                                     int* cursor, int* __restrict__ col,
                                                     int E4) {
    int i = blockIdx.x * blockDim.x + threadIdx.x;
    if (i >= E4) return;
    int4 a = stg2[2 * i];
    int4 b = stg2[2 * i + 1];
    int p0 = atomicAdd(&cursor[a.y], 1);
    int p1 = atomicAdd(&cursor[a.w], 1);
    int p2 = atomicAdd(&cursor[b.y], 1);
    int p3 = atomicAdd(&cursor[b.w], 1);
    col[p0] = a.x;
    col[p1] = a.z;
    col[p2] = b.x;
    col[p3] = b.z;
}

// non-vec4 fallback: direct fill
__global__ __launch_bounds__(256) void csr_fill_kernel(const int* __restrict__ src,
                                                       const int* __restrict__ dst,
                                                       int* cursor, int* __restrict__ col,
                                                       int E) {
    int e = blockIdx.x * blockDim.x + threadIdx.x;
    if (e >= E) return;
    int s = src[e], d = dst[e];
    int pos = atomicAdd(&cursor[d], 1);
    col[pos] = s;
}

// ---------------- register-tiled GEMM: t_h[N][128](f16) = (h[N][128](f32) @ W) * dinv[row] ----------------
#define TILE_R 64

__global__ __launch_bounds__(256, 2) void gemm128_tiled(const float* __restrict__ h,
                                                        const float* __restrict__ Wa,
                                                        const float* __restrict__ Wb,
                                                        const float* __restrict__ dinv,
                                                        __half* __restrict__ th,
                                                        int N, int ntiles) {
    __shared__ float hl[2][TILE_R * 128];

    const int lane = threadIdx.x & 63;
    const int wav  = threadIdx.x >> 6;
    const int jf4  = threadIdx.x & 31;
    const int rg   = threadIdx.x >> 5;

    const float* wptr;
    int wstride;
    if (Wb) { wptr = (jf4 < 16) ? (Wa + jf4 * 4) : (Wb + (jf4 - 16) * 4); wstride = 64; }
    else    { wptr = Wa + jf4 * 4; wstride = 128; }

    auto stage = [&](int buf, long long tile) {
        if (tile >= ntiles) return;
        long long row0 = tile * TILE_R;
        if (row0 + TILE_R <= N) {
            const float* gbase = h + row0 * 128 + (size_t)wav * (16 * 128) + lane * 4;
            float* lbase = &hl[buf][wav * (16 * 128)];
            #pragma unroll
            for (int m = 0; m < 8; ++m)
                gl_lds16(gbase + m * 256, lbase + m * 256);
        } else {
            for (int i = threadIdx.x; i < TILE_R * 32; i += 256) {
                int rl = i >> 5, k4 = i & 31;
                long long row = row0 + rl;
                float4 v = (row < N) ? ((const float4*)h)[row * 32 + k4]
                                     : make_float4(0.f, 0.f, 0.f, 0.f);
                *(float4*)&hl[buf][rl * 128 + k4 * 4] = v;
            }
        }
    };

    long long tile = blockIdx.x;
    stage(0, tile);
    __syncthreads();
    int cur = 0;

    for (; tile < ntiles; tile += gridDim.x) {
        stage(cur ^ 1, tile + gridDim.x);

        float4 acc[8];
        #pragma unroll
        for (int rr = 0; rr < 8; ++rr) acc[rr] = make_float4(0.f, 0.f, 0.f, 0.f);

        const float* hb = &hl[cur][rg * 8 * 128];
        #pragma unroll 4
        for (int k = 0; k < 128; k += 4) {
            float4 w0 = *(const float4*)&wptr[(size_t)(k + 0) * wstride];
            float4 w1 = *(const float4*)&wptr[(size_t)(k + 1) * wstride];
            float4 w2 = *(const float4*)&wptr[(size_t)(k + 2) * wstride];
            float4 w3 = *(const float4*)&wptr[(size_t)(k + 3) * wstride];
            #pragma unroll
            for (int rr = 0; rr < 8; ++rr) {
                float4 hv = *(const float4*)&hb[rr * 128 + k];
                acc[rr] = f4_fma(w0, hv.x, acc[rr]);
                acc[rr] = f4_fma(w1, hv.y, acc[rr]);
                acc[rr] = f4_fma(w2, hv.z, acc[rr]);
                acc[rr] = f4_fma(w3, hv.w, acc[rr]);
            }
        }

        long long row0 = tile * TILE_R;
        #pragma unroll
        for (int rr = 0; rr < 8; ++rr) {
            long long row = row0 + rg * 8 + rr;
            if (row < N) {
                float di = dinv[row];
                float4 r = acc[rr];
                r.x *= di; r.y *= di; r.z *= di; r.w *= di;
                store_half4(th + (size_t)row * 128 + jf4 * 4, r);
            }
        }
        __syncthreads();
        cur ^= 1;
    }
}

// ---------------- pull aggregation over f16 t ----------------
__global__ __launch_bounds__(256) void agg_pull_h_kernel(const __half* __restrict__ th,
                                                         const int* __restrict__ rowptr,
                                                         const int* __restrict__ col,
                                                         const float* __restrict__ dinv,
                                                         const float* __restrict__ b,
                                                         float* __restrict__ out,
                                                         int N, int relu) {
    int v = blockIdx.x * 16 + (threadIdx.x >> 4);
    int c = threadIdx.x & 15;   // 16B chunk (8 halves)
    if (v >= N) return;
    const uint4* tq = (const uint4*)th;  // row stride = 16 uint4
    int beg = rowptr[v], end = rowptr[v + 1];
    float a0[8] = {0,0,0,0,0,0,0,0}, a1[8] = {0,0,0,0,0,0,0,0};
    float a2[8] = {0,0,0,0,0,0,0,0}, a3[8] = {0,0,0,0,0,0,0,0};
    acc_half8(a0, tq[(size_t)v * 16 + c]);  // self-loop (pre-scaled)
    int e = beg;
    for (; e + 3 < end; e += 4) {
        int s0 = col[e], s1 = col[e + 1], s2 = col[e + 2], s3 = col[e + 3];
        uint4 r0 = tq[(size_t)s0 * 16 + c];
        uint4 r1 = tq[(size_t)s1 * 16 + c];
        uint4 r2 = tq[(size_t)s2 * 16 + c];
        uint4 r3 = tq[(size_t)s3 * 16 + c];
        acc_half8(a0, r0); acc_half8(a1, r1); acc_half8(a2, r2); acc_half8(a3, r3);
    }
    for (; e < end; ++e) acc_half8(a0, tq[(size_t)col[e] * 16 + c]);
    float di = dinv[v];
    float4 b0 = *(const float4*)(b + c * 8);
    float4 b1v = *(const float4*)(b + c * 8 + 4);
    float o[8];
    #pragma unroll
    for (int i = 0; i < 8; ++i) {
        float bb = (i < 4) ? (&b0.x)[i] : (&b1v.x)[i - 4];
        float s = (a0[i] + a1[i]) + (a2[i] + a3[i]);
        o[i] = fmaf(s, di, bb);
        if (relu) o[i] = fmaxf(o[i], 0.f);
    }
    float4* op = (float4*)(out + (size_t)v * 128 + c * 8);
    op[0] = make_float4(o[0], o[1], o[2], o[3]);
    op[1] = make_float4(o[4], o[5], o[6], o[7]);
}

// final: lane chunks c<8 -> mu, c>=8 -> logstd (split output)
__global__ __launch_bounds__(256) void agg_pull_final_h_kernel(const __half* __restrict__ th,
                                                               const int* __restrict__ rowptr,
                                                               const int* __restrict__ col,
                                                               const float* __restrict__ dinv,
                                                               const float* __restrict__ bmu,
                                                               const float* __restrict__ bls,
                                                               float* __restrict__ out,
                                                               int N) {
    int v = blockIdx.x * 16 + (threadIdx.x >> 4);
    int c = threadIdx.x & 15;
    if (v >= N) return;
    const uint4* tq = (const uint4*)th;
    int beg = rowptr[v], end = rowptr[v + 1];
    float a0[8] = {0,0,0,0,0,0,0,0}, a1[8] = {0,0,0,0,0,0,0,0};
    float a2[8] = {0,0,0,0,0,0,0,0}, a3[8] = {0,0,0,0,0,0,0,0};
    acc_half8(a0, tq[(size_t)v * 16 + c]);
    int e = beg;
    for (; e + 3 < end; e += 4) {
        int s0 = col[e], s1 = col[e + 1], s2 = col[e + 2], s3 = col[e + 3];
        uint4 r0 = tq[(size_t)s0 * 16 + c];
        uint4 r1 = tq[(size_t)s1 * 16 + c];
        uint4 r2 = tq[(size_t)s2 * 16 + c];
        uint4 r3 = tq[(size_t)s3 * 16 + c];
        acc_half8(a0, r0); acc_half8(a1, r1); acc_half8(a2, r2); acc_half8(a3, r3);
    }
    for (; e < end; ++e) acc_half8(a0, tq[(size_t)col[e] * 16 + c]);
    float di = dinv[v];
    const float* bp = (c < 8) ? (bmu + c * 8) : (bls + (c - 8) * 8);
    float* obase = (c < 8) ? (out + (size_t)v * 64 + c * 8)
                           : (out + (size_t)N * 64 + (size_t)v * 64 + (size_t)(c - 8) * 8);
    float4 b0 = *(const float4*)bp;
    float4 b1v = *(const float4*)(bp + 4);
    float o[8];
    #pragma unroll
    for (int i = 0; i < 8; ++i) {
        float bb = (i < 4) ? (&b0.x)[i] : (&b1v.x)[i - 4];
        float s = (a0[i] + a1[i]) + (a2[i] + a3[i]);
        o[i] = fmaf(s, di, bb);
    }
    ((float4*)obase)[0] = make_float4(o[0], o[1], o[2], o[3]);
    ((float4*)obase)[1] = make_float4(o[4], o[5], o[6], o[7]);
}

// ---------------- fallback (atomic scatter, f32) kernels ----------------
__global__ __launch_bounds__(256) void deg_init_kernel(float* deg, int N) {
    int i = blockIdx.x * blockDim.x + threadIdx.x;
    if (i < N) deg[i] = 1.0f;
}
__global__ __launch_bounds__(256) void deg_count_kernel(const int* __restrict__ dst, float* deg, int E) {
    int i = blockIdx.x * blockDim.x + threadIdx.x;
    if (i < E) unsafeAtomicAdd(&deg[dst[i]], 1.0f);
}
__global__ __launch_bounds__(256) void deg_rsqrt_kernel(float* deg, int N) {
    int i = blockIdx.x * blockDim.x + threadIdx.x;
    if (i < N) deg[i] = rsqrtf(deg[i]);
}
__global__ __launch_bounds__(256) void gemm128_kernel(const float* __restrict__ h,
                                                      const float* __restrict__ Wa,
                                                      const float* __restrict__ Wb,
                                                      float* __restrict__ t,
                                                      int N, int relu) {
    __shared__ float Wl[128 * 128];
    __shared__ float hl[2][128];
    for (int i = threadIdx.x; i < 128 * 128; i += 256) {
        int k = i >> 7, j = i & 127;
        float w;
        if (Wb) w = (j < 64) ? Wa[k * 64 + j] : Wb[k * 64 + (j - 64)];
        else    w = Wa[i];
        Wl[i] = w;
    }
    __syncthreads();
    int col = threadIdx.x & 127;
    int r   = threadIdx.x >> 7;
    for (long long pair = blockIdx.x; pair * 2 < N; pair += gridDim.x) {
        int row0 = (int)(pair * 2);
        {
            int rr = threadIdx.x >> 7, k = threadIdx.x & 127;
            int row = row0 + rr;
            float v = (row < N) ? h[(size_t)row * 128 + k] : 0.0f;
            if (relu) v = fmaxf(v, 0.0f);
            hl[rr][k] = v;
        }
        __syncthreads();
        float acc = 0.0f;
        #pragma unroll
        for (int k = 0; k < 128; k += 4) {
            float4 hv = *(const float4*)&hl[r][k];
            acc += hv.x * Wl[(k + 0) * 128 + col];
            acc += hv.y * Wl[(k + 1) * 128 + col];
            acc += hv.z * Wl[(k + 2) * 128 + col];
            acc += hv.w * Wl[(k + 3) * 128 + col];
        }
        int row = row0 + r;
        if (row < N) t[(size_t)row * 128 + col] = acc;
        __syncthreads();
    }
}
__global__ __launch_bounds__(256) void init_self_kernel(const float4* __restrict__ t4,
                                                        const float* __restrict__ dinv,
                                                        const float* __restrict__ b,
                                                        float4* __restrict__ out, int N) {
    int idx = blockIdx.x * blockDim.x + threadIdx.x;
    int v = idx >> 5, c = idx & 31;
    if (v >= N) return;
    float di = dinv[v];
    float s = di * di;
    float4 x = t4[(size_t)v * 32 + c];
    float4 bb = ((const float4*)b)[c];
    out[(size_t)v * 32 + c] = make_float4(fmaf(x.x, s, bb.x), fmaf(x.y, s, bb.y),
                                          fmaf(x.z, s, bb.z), fmaf(x.w, s, bb.w));
}
__global__ __launch_bounds__(256) void init_final_kernel(const float4* __restrict__ t4,
                                                         const float* __restrict__ dinv,
                                                         const float* __restrict__ bmu,
                                                         const float* __restrict__ bls,
                                                         float4* __restrict__ out4, int N) {
    int idx = blockIdx.x * blockDim.x + threadIdx.x;
    int v = idx >> 5, c = idx & 31;
    if (v >= N) return;
    int half = c >> 4, cc = c & 15;
    float di = dinv[v];
    float s = di * di;
    float4 x = t4[(size_t)v * 32 + c];
    float4 bb = half ? ((const float4*)bls)[cc] : ((const float4*)bmu)[cc];
    out4[(size_t)half * N * 16 + (size_t)v * 16 + cc] =
        make_float4(fmaf(x.x, s, bb.x), fmaf(x.y, s, bb.y),
                    fmaf(x.z, s, bb.z), fmaf(x.w, s, bb.w));
}
__global__ __launch_bounds__(256) void agg_edge_kernel(const float4* __restrict__ t4,
                                                       const int* __restrict__ src,
                                                       const int* __restrict__ dst,
                                                       const float* __restrict__ dinv,
                                                       float* __restrict__ out, int E) {
    int idx = blockIdx.x * blockDim.x + threadIdx.x;
    int e = idx >> 5, c = idx & 31;
    if (e >= E) return;
    int s = src[e], d = dst[e];
    float w = dinv[s] * dinv[d];
    float4 v = t4[(size_t)s * 32 + c];
    float* o = out + (size_t)d * 128 + c * 4;
    unsafeAtomicAdd(o + 0, v.x * w);
    unsafeAtomicAdd(o + 1, v.y * w);
    unsafeAtomicAdd(o + 2, v.z * w);
    unsafeAtomicAdd(o + 3, v.w * w);
}
__global__ __launch_bounds__(256) void agg_edge_final_kernel(const float4* __restrict__ t4,
                                                             const int* __restrict__ src,
                                                             const int* __restrict__ dst,
                                                             const float* __restrict__ dinv,
                                                             float* __restrict__ out, int N, int E) {
    int idx = blockIdx.x * blockDim.x + threadIdx.x;
    int e = idx >> 5, c = idx & 31;
    if (e >= E) return;
    int s = src[e], d = dst[e];
    int half = c >> 4, cc = c & 15;
    float w = dinv[s] * dinv[d];
    float4 v = t4[(size_t)s * 32 + c];
    float* o = out + (size_t)half * N * 64 + (size_t)d * 64 + cc * 4;
    unsafeAtomicAdd(o + 0, v.x * w);
    unsafeAtomicAdd(o + 1, v.y * w);
    unsafeAtomicAdd(o + 2, v.z * w);
    unsafeAtomicAdd(o + 3, v.w * w);
}

// ---------------- launch ----------------
extern "C" void kernel_launch(void* const* d_in, const int* in_sizes, int n_in,
                              void* d_out, int out_size, void* d_ws, size_t ws_size,
                              hipStream_t stream) {
    const float* x   = (const float*)d_in[0];
    const int*   ei  = (const int*)d_in[1];
    const float* W1  = (const float*)d_in[2];
    const float* b1  = (const float*)d_in[3];
    const float* W2  = (const float*)d_in[4];
    const float* b2  = (const float*)d_in[5];
    const float* Wmu = (const float*)d_in[6];
    const float* bmu = (const float*)d_in[7];
    const float* Wls = (const float*)d_in[8];
    const float* bls = (const float*)d_in[9];

    const int N = in_sizes[0] / 128;
    const int E = in_sizes[1] / 2;
    const int* src = ei;
    const int* dst = ei + E;

    float* out = (float*)d_out;  // f32 h buffer for hidden layers, final mu|ls

    auto align256 = [](size_t o) { return (o + 255) & ~(size_t)255; };
    const int B1 = (N + SCAN_CHUNK - 1) / SCAN_CHUNK;
    const int NB = (N + (1 << BSHIFT) - 1) >> BSHIFT;

    size_t off = 0;
    size_t o_dinv   = off; off = align256(off + (size_t)N * 4);
    size_t o_t      = off; off = align256(off + (size_t)N * 128 * 4);  // f32 for fallback; f16 path uses half
    size_t o_rowptr = off; off = align256(off + (size_t)(N + 1) * 4);
    size_t o_cursor = off; off = align256(off + (size_t)N * 4);        // also cnt
    size_t o_bsum   = off; off = align256(off + (size_t)B1 * 4);
    size_t o_col    = off; off = align256(off + (size_t)E * 4);
    size_t o_bcur   = off; off = align256(off + (size_t)NB * 4);
    size_t o_stg    = off; off = align256(off + (size_t)E * 8);
    size_t need = off;
    size_t need_nostg = o_bcur;  // layout up to col suffices for direct-fill path

    float*  dinv = (float*)((char*)d_ws + o_dinv);
    float*  tf   = (float*)((char*)d_ws + o_t);   // fallback f32 t
    __half* th   = (__half*)((char*)d_ws + o_t);  // main-path f16 t

    const int TB = 256;
    int gN = (N + TB - 1) / TB;
    int gE = (E + TB - 1) / TB;
    int ntiles = (N + TILE_R - 1) / TILE_R;

    if (ws_size >= need_nostg) {
        int* rowptr = (int*)((char*)d_ws + o_rowptr);
        int* cursor = (int*)((char*)d_ws + o_cursor);
        int* bsum   = (int*)((char*)d_ws + o_bsum);
        int* col    = (int*)((char*)d_ws + o_col);
        int* bcur   = (int*)((char*)d_ws + o_bcur);
        int2* stg   = (int2*)((char*)d_ws + o_stg);

        const bool vec4 = ((E & 3) == 0) && ((((uintptr_t)ei) & 15) == 0) && (ws_size >= need);
        const int E4 = E >> 2;
        int gE4 = (E4 + TB - 1) / TB;

        // CSR build
        hipMemsetAsync(cursor, 0, (size_t)N * 4, stream);
        if (vec4)
            cnt_count4_kernel<<<gE4, TB, 0, stream>>>((const int4*)dst, cursor, E4);
        else
            cnt_count_kernel<<<gE, TB, 0, stream>>>(dst, cursor, E);
        scan_reduce_kernel<<<B1, TB, 0, stream>>>(cursor, bsum, N);
        scan_bsum_kernel<<<1, 64, 0, stream>>>(bsum, B1, rowptr + N, E);
        scan_write_kernel<<<B1, TB, 0, stream>>>(cursor, bsum, rowptr, cursor, dinv, bcur, N);
        if (vec4) {
            bin4_kernel<<<gE4, TB, 0, stream>>>((const int4*)src, (const int4*)dst, bcur, stg, E4);
            fillB4_kernel<<<gE4, TB, 0, stream>>>((const int4*)stg, cursor, col, E4);
        } else {
            csr_fill_kernel<<<gE, TB, 0, stream>>>(src, dst, cursor, col, E);
        }

        int gPull = (N + 15) / 16;
        // layer 1: t = f16((x @ W1) * dinv)
        gemm128_tiled<<<512, TB, 0, stream>>>(x, W1, nullptr, dinv, th, N, ntiles);
        agg_pull_h_kernel<<<gPull, TB, 0, stream>>>(th, rowptr, col, dinv, b1, out, N, 1);
        // layer 2
        gemm128_tiled<<<512, TB, 0, stream>>>(out, W2, nullptr, dinv, th, N, ntiles);
        agg_pull_h_kernel<<<gPull, TB, 0, stream>>>(th, rowptr, col, dinv, b2, out, N, 1);
        // layer 3+4 fused columns [Wmu|Wls]
        gemm128_tiled<<<512, TB, 0, stream>>>(out, Wmu, Wls, dinv, th, N, ntiles);
        agg_pull_final_h_kernel<<<gPull, TB, 0, stream>>>(th, rowptr, col, dinv, bmu, bls, out, N);
    } else {
        // fallback: atomic scatter path (f32)
        int gN32  = (N * 32 + TB - 1) / TB;
        int gE32h = (int)(((long long)E * 32 + TB - 1) / TB);
        deg_init_kernel<<<gN, TB, 0, stream>>>(dinv, N);
        deg_count_kernel<<<gE, TB, 0, stream>>>(dst, dinv, E);
        deg_rsqrt_kernel<<<gN, TB, 0, stream>>>(dinv, N);

        gemm128_kernel<<<2048, TB, 0, stream>>>(x, W1, nullptr, tf, N, 0);
        init_self_kernel<<<gN32, TB, 0, stream>>>((const float4*)tf, dinv, b1, (float4*)out, N);
        agg_edge_kernel<<<gE32h, TB, 0, stream>>>((const float4*)tf, src, dst, dinv, out, E);

        gemm128_kernel<<<2048, TB, 0, stream>>>(out, W2, nullptr, tf, N, 1);
        init_self_kernel<<<gN32, TB, 0, stream>>>((const float4*)tf, dinv, b2, (float4*)out, N);
        agg_edge_kernel<<<gE32h, TB, 0, stream>>>((const float4*)tf, src, dst, dinv, out, E);

        gemm128_kernel<<<2048, TB, 0, stream>>>(out, Wmu, Wls, tf, N, 1);
        init_final_kernel<<<gN32, TB, 0, stream>>>((const float4*)tf, dinv, bmu, bls, (float4*)out, N);
        agg_edge_final_kernel<<<gE32h, TB, 0, stream>>>((const float4*)tf, src, dst, dinv, out, N, E);
    }
}

// Round 13
// 535.351 us; speedup vs baseline: 1.6471x; 1.6471x over previous
//
#include <hip/hip_runtime.h>
#include <hip/hip_fp16.h>
#include <hip/hip_bf16.h>

// ---------------- small helpers ----------------
__device__ __forceinline__ float4 f4_fma(float4 a, float s, float4 acc) {
    acc.x = fmaf(a.x, s, acc.x); acc.y = fmaf(a.y, s, acc.y);
    acc.z = fmaf(a.z, s, acc.z); acc.w = fmaf(a.w, s, acc.w);
    return acc;
}

typedef const __attribute__((address_space(1))) unsigned int* gas_u32;
typedef __attribute__((address_space(3))) unsigned int* las_u32;

__device__ __forceinline__ void gl_lds16(const float* g, float* l) {
    __builtin_amdgcn_global_load_lds((gas_u32)(const void*)g, (las_u32)(void*)l, 16, 0, 0);
}

// f32x4 -> f16x4 packed store (8 B)
__device__ __forceinline__ void store_half4(__half* p, float4 v) {
    union { __half2 h[2]; uint2 u; } pk;
    pk.h[0] = __floats2half2_rn(v.x, v.y);
    pk.h[1] = __floats2half2_rn(v.z, v.w);
    *(uint2*)p = pk.u;
}

// accumulate 8 halves (one uint4) into 8 f32 accumulators
__device__ __forceinline__ void acc_half8(float* acc, uint4 raw) {
    union { uint4 u; __half2 h[4]; } pk; pk.u = raw;
    float2 f0 = __half22float2(pk.h[0]);
    float2 f1 = __half22float2(pk.h[1]);
    float2 f2 = __half22float2(pk.h[2]);
    float2 f3 = __half22float2(pk.h[3]);
    acc[0] += f0.x; acc[1] += f0.y; acc[2] += f1.x; acc[3] += f1.y;
    acc[4] += f2.x; acc[5] += f2.y; acc[6] += f3.x; acc[7] += f3.y;
}

// ---------------- degree count ----------------
__global__ __launch_bounds__(256) void cnt_count4_kernel(const int4* __restrict__ dst4, int* cnt, int E4) {
    int i = blockIdx.x * blockDim.x + threadIdx.x;
    if (i < E4) {
        int4 d = dst4[i];
        atomicAdd(&cnt[d.x], 1);
        atomicAdd(&cnt[d.y], 1);
        atomicAdd(&cnt[d.z], 1);
        atomicAdd(&cnt[d.w], 1);
    }
}
__global__ __launch_bounds__(256) void cnt_count_kernel(const int* __restrict__ dst, int* cnt, int E) {
    int i = blockIdx.x * blockDim.x + threadIdx.x;
    if (i < E) atomicAdd(&cnt[dst[i]], 1);
}

// ---------------- exclusive scan (N ~ 100k) ----------------
#define SCAN_CHUNK 4096  // 256 threads * 16

__global__ __launch_bounds__(256) void scan_reduce_kernel(const int* __restrict__ cnt, int* bsum, int N) {
    __shared__ int sdata[256];
    int base = blockIdx.x * SCAN_CHUNK;
    int s = 0;
    for (int k = 0; k < 16; ++k) {
        int i = base + k * 256 + threadIdx.x;
        if (i < N) s += cnt[i];
    }
    sdata[threadIdx.x] = s;
    __syncthreads();
    for (int off = 128; off > 0; off >>= 1) {
        if (threadIdx.x < off) sdata[threadIdx.x] += sdata[threadIdx.x + off];
        __syncthreads();
    }
    if (threadIdx.x == 0) bsum[blockIdx.x] = sdata[0];
}

__global__ void scan_bsum_kernel(int* bsum, int B, int* rowptr_end, int E) {
    if (threadIdx.x == 0 && blockIdx.x == 0) {
        int run = 0;
        for (int i = 0; i < B; ++i) { int v = bsum[i]; bsum[i] = run; run += v; }
        *rowptr_end = E;  // rowptr[N] = E
    }
}

// emits rowptr, cursor (=rowptr copy), dinv
__global__ __launch_bounds__(256) void scan_write_kernel(const int* __restrict__ cnt,
                                                         const int* __restrict__ bsum,
                                                         int* rowptr, int* cursor,
                                                         float* dinv, int N) {
    __shared__ int sdata[256];
    int base = blockIdx.x * SCAN_CHUNK;
    int tbase = base + threadIdx.x * 16;
    int loc[16];
    int s = 0;
    for (int k = 0; k < 16; ++k) {
        int i = tbase + k;
        int v = (i < N) ? cnt[i] : 0;
        loc[k] = s; s += v;
    }
    sdata[threadIdx.x] = s;
    __syncthreads();
    for (int off = 1; off < 256; off <<= 1) {
        int v = sdata[threadIdx.x];
        int add = (threadIdx.x >= off) ? sdata[threadIdx.x - off] : 0;
        __syncthreads();
        sdata[threadIdx.x] = v + add;
        __syncthreads();
    }
    int texcl = (threadIdx.x == 0) ? 0 : sdata[threadIdx.x - 1];
    int boff = bsum[blockIdx.x];
    for (int k = 0; k < 16; ++k) {
        int i = tbase + k;
        if (i < N) {
            int rp = boff + texcl + loc[k];
            rowptr[i] = rp;
            cursor[i] = rp;
            dinv[i] = rsqrtf((float)(cnt[i] + 1));
        }
    }
}

// ---------------- XCD-partitioned csr fill ----------------
// A dst node's CSR slots span <=2 cache lines; write amplification (R9 PMC:
// 107MB writeback for 6.4MB data) comes from the same line being dirtied by
// multiple non-coherent XCD L2s at different times. Partition dst-space into
// 8 ranges and let blocks with blockIdx%8==p handle range p: consecutive
// blocks round-robin across XCDs (heuristic; correctness never depends on it),
// so each XCD's writes stay in a ~0.8MB L2-resident window. Costs 8x edge
// re-read (102MB streaming, ~20us) to kill ~90MB of partial-line writeback.
#define NPART 8

__global__ __launch_bounds__(256) void csr_fill_part4_kernel(const int4* __restrict__ src4,
                                                             const int4* __restrict__ dst4,
                                                             int* cursor, int* __restrict__ col,
                                                             int E4, int pshift) {
    int part = blockIdx.x & (NPART - 1);
    int i = (blockIdx.x >> 3) * blockDim.x + threadIdx.x;
    if (i >= E4) return;
    int4 s = src4[i];
    int4 d = dst4[i];
    if ((d.x >> pshift) == part) { int p = atomicAdd(&cursor[d.x], 1); col[p] = s.x; }
    if ((d.y >> pshift) == part) { int p = atomicAdd(&cursor[d.y], 1); col[p] = s.y; }
    if ((d.z >> pshift) == part) { int p = atomicAdd(&cursor[d.z], 1); col[p] = s.z; }
    if ((d.w >> pshift) == part) { int p = atomicAdd(&cursor[d.w], 1); col[p] = s.w; }
}

// non-vec4 fallback: direct fill
__global__ __launch_bounds__(256) void csr_fill_kernel(const int* __restrict__ src,
                                                       const int* __restrict__ dst,
                                                       int* cursor, int* __restrict__ col,
                                                       int E) {
    int e = blockIdx.x * blockDim.x + threadIdx.x;
    if (e >= E) return;
    int s = src[e], d = dst[e];
    int pos = atomicAdd(&cursor[d], 1);
    col[pos] = s;
}

// ---------------- register-tiled GEMM: t_h[N][128](f16) = (h[N][128](f32) @ W) * dinv[row] ----------------
#define TILE_R 64

__global__ __launch_bounds__(256, 2) void gemm128_tiled(const float* __restrict__ h,
                                                        const float* __restrict__ Wa,
                                                        const float* __restrict__ Wb,
                                                        const float* __restrict__ dinv,
                                                        __half* __restrict__ th,
                                                        int N, int ntiles) {
    __shared__ float hl[2][TILE_R * 128];

    const int lane = threadIdx.x & 63;
    const int wav  = threadIdx.x >> 6;
    const int jf4  = threadIdx.x & 31;
    const int rg   = threadIdx.x >> 5;

    const float* wptr;
    int wstride;
    if (Wb) { wptr = (jf4 < 16) ? (Wa + jf4 * 4) : (Wb + (jf4 - 16) * 4); wstride = 64; }
    else    { wptr = Wa + jf4 * 4; wstride = 128; }

    auto stage = [&](int buf, long long tile) {
        if (tile >= ntiles) return;
        long long row0 = tile * TILE_R;
        if (row0 + TILE_R <= N) {
            const float* gbase = h + row0 * 128 + (size_t)wav * (16 * 128) + lane * 4;
            float* lbase = &hl[buf][wav * (16 * 128)];
            #pragma unroll
            for (int m = 0; m < 8; ++m)
                gl_lds16(gbase + m * 256, lbase + m * 256);
        } else {
            for (int i = threadIdx.x; i < TILE_R * 32; i += 256) {
                int rl = i >> 5, k4 = i & 31;
                long long row = row0 + rl;
                float4 v = (row < N) ? ((const float4*)h)[row * 32 + k4]
                                     : make_float4(0.f, 0.f, 0.f, 0.f);
                *(float4*)&hl[buf][rl * 128 + k4 * 4] = v;
            }
        }
    };

    long long tile = blockIdx.x;
    stage(0, tile);
    __syncthreads();
    int cur = 0;

    for (; tile < ntiles; tile += gridDim.x) {
        stage(cur ^ 1, tile + gridDim.x);

        float4 acc[8];
        #pragma unroll
        for (int rr = 0; rr < 8; ++rr) acc[rr] = make_float4(0.f, 0.f, 0.f, 0.f);

        const float* hb = &hl[cur][rg * 8 * 128];
        #pragma unroll 4
        for (int k = 0; k < 128; k += 4) {
            float4 w0 = *(const float4*)&wptr[(size_t)(k + 0) * wstride];
            float4 w1 = *(const float4*)&wptr[(size_t)(k + 1) * wstride];
            float4 w2 = *(const float4*)&wptr[(size_t)(k + 2) * wstride];
            float4 w3 = *(const float4*)&wptr[(size_t)(k + 3) * wstride];
            #pragma unroll
            for (int rr = 0; rr < 8; ++rr) {
                float4 hv = *(const float4*)&hb[rr * 128 + k];
                acc[rr] = f4_fma(w0, hv.x, acc[rr]);
                acc[rr] = f4_fma(w1, hv.y, acc[rr]);
                acc[rr] = f4_fma(w2, hv.z, acc[rr]);
                acc[rr] = f4_fma(w3, hv.w, acc[rr]);
            }
        }

        long long row0 = tile * TILE_R;
        #pragma unroll
        for (int rr = 0; rr < 8; ++rr) {
            long long row = row0 + rg * 8 + rr;
            if (row < N) {
                float di = dinv[row];
                float4 r = acc[rr];
                r.x *= di; r.y *= di; r.z *= di; r.w *= di;
                store_half4(th + (size_t)row * 128 + jf4 * 4, r);
            }
        }
        __syncthreads();
        cur ^= 1;
    }
}

// ---------------- pull aggregation over f16 t ----------------
__global__ __launch_bounds__(256) void agg_pull_h_kernel(const __half* __restrict__ th,
                                                         const int* __restrict__ rowptr,
                                                         const int* __restrict__ col,
                                                         const float* __restrict__ dinv,
                                                         const float* __restrict__ b,
                                                         float* __restrict__ out,
                                                         int N, int relu) {
    int v = blockIdx.x * 16 + (threadIdx.x >> 4);
    int c = threadIdx.x & 15;   // 16B chunk (8 halves)
    if (v >= N) return;
    const uint4* tq = (const uint4*)th;  // row stride = 16 uint4
    int beg = rowptr[v], end = rowptr[v + 1];
    float a0[8] = {0,0,0,0,0,0,0,0}, a1[8] = {0,0,0,0,0,0,0,0};
    float a2[8] = {0,0,0,0,0,0,0,0}, a3[8] = {0,0,0,0,0,0,0,0};
    acc_half8(a0, tq[(size_t)v * 16 + c]);  // self-loop (pre-scaled)
    int e = beg;
    for (; e + 3 < end; e += 4) {
        int s0 = col[e], s1 = col[e + 1], s2 = col[e + 2], s3 = col[e + 3];
        uint4 r0 = tq[(size_t)s0 * 16 + c];
        uint4 r1 = tq[(size_t)s1 * 16 + c];
        uint4 r2 = tq[(size_t)s2 * 16 + c];
        uint4 r3 = tq[(size_t)s3 * 16 + c];
        acc_half8(a0, r0); acc_half8(a1, r1); acc_half8(a2, r2); acc_half8(a3, r3);
    }
    for (; e < end; ++e) acc_half8(a0, tq[(size_t)col[e] * 16 + c]);
    float di = dinv[v];
    float4 b0 = *(const float4*)(b + c * 8);
    float4 b1v = *(const float4*)(b + c * 8 + 4);
    float o[8];
    #pragma unroll
    for (int i = 0; i < 8; ++i) {
        float bb = (i < 4) ? (&b0.x)[i] : (&b1v.x)[i - 4];
        float s = (a0[i] + a1[i]) + (a2[i] + a3[i]);
        o[i] = fmaf(s, di, bb);
        if (relu) o[i] = fmaxf(o[i], 0.f);
    }
    float4* op = (float4*)(out + (size_t)v * 128 + c * 8);
    op[0] = make_float4(o[0], o[1], o[2], o[3]);
    op[1] = make_float4(o[4], o[5], o[6], o[7]);
}

// final: lane chunks c<8 -> mu, c>=8 -> logstd (split output)
__global__ __launch_bounds__(256) void agg_pull_final_h_kernel(const __half* __restrict__ th,
                                                               const int* __restrict__ rowptr,
                                                               const int* __restrict__ col,
                                                               const float* __restrict__ dinv,
                                                               const float* __restrict__ bmu,
                                                               const float* __restrict__ bls,
                                                               float* __restrict__ out,
                                                               int N) {
    int v = blockIdx.x * 16 + (threadIdx.x >> 4);
    int c = threadIdx.x & 15;
    if (v >= N) return;
    const uint4* tq = (const uint4*)th;
    int beg = rowptr[v], end = rowptr[v + 1];
    float a0[8] = {0,0,0,0,0,0,0,0}, a1[8] = {0,0,0,0,0,0,0,0};
    float a2[8] = {0,0,0,0,0,0,0,0}, a3[8] = {0,0,0,0,0,0,0,0};
    acc_half8(a0, tq[(size_t)v * 16 + c]);
    int e = beg;
    for (; e + 3 < end; e += 4) {
        int s0 = col[e], s1 = col[e + 1], s2 = col[e + 2], s3 = col[e + 3];
        uint4 r0 = tq[(size_t)s0 * 16 + c];
        uint4 r1 = tq[(size_t)s1 * 16 + c];
        uint4 r2 = tq[(size_t)s2 * 16 + c];
        uint4 r3 = tq[(size_t)s3 * 16 + c];
        acc_half8(a0, r0); acc_half8(a1, r1); acc_half8(a2, r2); acc_half8(a3, r3);
    }
    for (; e < end; ++e) acc_half8(a0, tq[(size_t)col[e] * 16 + c]);
    float di = dinv[v];
    const float* bp = (c < 8) ? (bmu + c * 8) : (bls + (c - 8) * 8);
    float* obase = (c < 8) ? (out + (size_t)v * 64 + c * 8)
                           : (out + (size_t)N * 64 + (size_t)v * 64 + (size_t)(c - 8) * 8);
    float4 b0 = *(const float4*)bp;
    float4 b1v = *(const float4*)(bp + 4);
    float o[8];
    #pragma unroll
    for (int i = 0; i < 8; ++i) {
        float bb = (i < 4) ? (&b0.x)[i] : (&b1v.x)[i - 4];
        float s = (a0[i] + a1[i]) + (a2[i] + a3[i]);
        o[i] = fmaf(s, di, bb);
    }
    ((float4*)obase)[0] = make_float4(o[0], o[1], o[2], o[3]);
    ((float4*)obase)[1] = make_float4(o[4], o[5], o[6], o[7]);
}

// ---------------- fallback (atomic scatter, f32) kernels ----------------
__global__ __launch_bounds__(256) void deg_init_kernel(float* deg, int N) {
    int i = blockIdx.x * blockDim.x + threadIdx.x;
    if (i < N) deg[i] = 1.0f;
}
__global__ __launch_bounds__(256) void deg_count_kernel(const int* __restrict__ dst, float* deg, int E) {
    int i = blockIdx.x * blockDim.x + threadIdx.x;
    if (i < E) unsafeAtomicAdd(&deg[dst[i]], 1.0f);
}
__global__ __launch_bounds__(256) void deg_rsqrt_kernel(float* deg, int N) {
    int i = blockIdx.x * blockDim.x + threadIdx.x;
    if (i < N) deg[i] = rsqrtf(deg[i]);
}
__global__ __launch_bounds__(256) void gemm128_kernel(const float* __restrict__ h,
                                                      const float* __restrict__ Wa,
                                                      const float* __restrict__ Wb,
                                                      float* __restrict__ t,
                                                      int N, int relu) {
    __shared__ float Wl[128 * 128];
    __shared__ float hl[2][128];
    for (int i = threadIdx.x; i < 128 * 128; i += 256) {
        int k = i >> 7, j = i & 127;
        float w;
        if (Wb) w = (j < 64) ? Wa[k * 64 + j] : Wb[k * 64 + (j - 64)];
        else    w = Wa[i];
        Wl[i] = w;
    }
    __syncthreads();
    int col = threadIdx.x & 127;
    int r   = threadIdx.x >> 7;
    for (long long pair = blockIdx.x; pair * 2 < N; pair += gridDim.x) {
        int row0 = (int)(pair * 2);
        {
            int rr = threadIdx.x >> 7, k = threadIdx.x & 127;
            int row = row0 + rr;
            float v = (row < N) ? h[(size_t)row * 128 + k] : 0.0f;
            if (relu) v = fmaxf(v, 0.0f);
            hl[rr][k] = v;
        }
        __syncthreads();
        float acc = 0.0f;
        #pragma unroll
        for (int k = 0; k < 128; k += 4) {
            float4 hv = *(const float4*)&hl[r][k];
            acc += hv.x * Wl[(k + 0) * 128 + col];
            acc += hv.y * Wl[(k + 1) * 128 + col];
            acc += hv.z * Wl[(k + 2) * 128 + col];
            acc += hv.w * Wl[(k + 3) * 128 + col];
        }
        int row = row0 + r;
        if (row < N) t[(size_t)row * 128 + col] = acc;
        __syncthreads();
    }
}
__global__ __launch_bounds__(256) void init_self_kernel(const float4* __restrict__ t4,
                                                        const float* __restrict__ dinv,
                                                        const float* __restrict__ b,
                                                        float4* __restrict__ out, int N) {
    int idx = blockIdx.x * blockDim.x + threadIdx.x;
    int v = idx >> 5, c = idx & 31;
    if (v >= N) return;
    float di = dinv[v];
    float s = di * di;
    float4 x = t4[(size_t)v * 32 + c];
    float4 bb = ((const float4*)b)[c];
    out[(size_t)v * 32 + c] = make_float4(fmaf(x.x, s, bb.x), fmaf(x.y, s, bb.y),
                                          fmaf(x.z, s, bb.z), fmaf(x.w, s, bb.w));
}
__global__ __launch_bounds__(256) void init_final_kernel(const float4* __restrict__ t4,
                                                         const float* __restrict__ dinv,
                                                         const float* __restrict__ bmu,
                                                         const float* __restrict__ bls,
                                                         float4* __restrict__ out4, int N) {
    int idx = blockIdx.x * blockDim.x + threadIdx.x;
    int v = idx >> 5, c = idx & 31;
    if (v >= N) return;
    int half = c >> 4, cc = c & 15;
    float di = dinv[v];
    float s = di * di;
    float4 x = t4[(size_t)v * 32 + c];
    float4 bb = half ? ((const float4*)bls)[cc] : ((const float4*)bmu)[cc];
    out4[(size_t)half * N * 16 + (size_t)v * 16 + cc] =
        make_float4(fmaf(x.x, s, bb.x), fmaf(x.y, s, bb.y),
                    fmaf(x.z, s, bb.z), fmaf(x.w, s, bb.w));
}
__global__ __launch_bounds__(256) void agg_edge_kernel(const float4* __restrict__ t4,
                                                       const int* __restrict__ src,
                                                       const int* __restrict__ dst,
                                                       const float* __restrict__ dinv,
                                                       float* __restrict__ out, int E) {
    int idx = blockIdx.x * blockDim.x + threadIdx.x;
    int e = idx >> 5, c = idx & 31;
    if (e >= E) return;
    int s = src[e], d = dst[e];
    float w = dinv[s] * dinv[d];
    float4 v = t4[(size_t)s * 32 + c];
    float* o = out + (size_t)d * 128 + c * 4;
    unsafeAtomicAdd(o + 0, v.x * w);
    unsafeAtomicAdd(o + 1, v.y * w);
    unsafeAtomicAdd(o + 2, v.z * w);
    unsafeAtomicAdd(o + 3, v.w * w);
}
__global__ __launch_bounds__(256) void agg_edge_final_kernel(const float4* __restrict__ t4,
                                                             const int* __restrict__ src,
                                                             const int* __restrict__ dst,
                                                             const float* __restrict__ dinv,
                                                             float* __restrict__ out, int N, int E) {
    int idx = blockIdx.x * blockDim.x + threadIdx.x;
    int e = idx >> 5, c = idx & 31;
    if (e >= E) return;
    int s = src[e], d = dst[e];
    int half = c >> 4, cc = c & 15;
    float w = dinv[s] * dinv[d];
    float4 v = t4[(size_t)s * 32 + c];
    float* o = out + (size_t)half * N * 64 + (size_t)d * 64 + cc * 4;
    unsafeAtomicAdd(o + 0, v.x * w);
    unsafeAtomicAdd(o + 1, v.y * w);
    unsafeAtomicAdd(o + 2, v.z * w);
    unsafeAtomicAdd(o + 3, v.w * w);
}

// ---------------- launch ----------------
extern "C" void kernel_launch(void* const* d_in, const int* in_sizes, int n_in,
                              void* d_out, int out_size, void* d_ws, size_t ws_size,
                              hipStream_t stream) {
    const float* x   = (const float*)d_in[0];
    const int*   ei  = (const int*)d_in[1];
    const float* W1  = (const float*)d_in[2];
    const float* b1  = (const float*)d_in[3];
    const float* W2  = (const float*)d_in[4];
    const float* b2  = (const float*)d_in[5];
    const float* Wmu = (const float*)d_in[6];
    const float* bmu = (const float*)d_in[7];
    const float* Wls = (const float*)d_in[8];
    const float* bls = (const float*)d_in[9];

    const int N = in_sizes[0] / 128;
    const int E = in_sizes[1] / 2;
    const int* src = ei;
    const int* dst = ei + E;

    float* out = (float*)d_out;  // f32 h buffer for hidden layers, final mu|ls

    auto align256 = [](size_t o) { return (o + 255) & ~(size_t)255; };
    const int B1 = (N + SCAN_CHUNK - 1) / SCAN_CHUNK;

    size_t off = 0;
    size_t o_dinv   = off; off = align256(off + (size_t)N * 4);
    size_t o_t      = off; off = align256(off + (size_t)N * 128 * 4);  // f32 for fallback; f16 path uses half
    size_t o_rowptr = off; off = align256(off + (size_t)(N + 1) * 4);
    size_t o_cursor = off; off = align256(off + (size_t)N * 4);        // also cnt
    size_t o_bsum   = off; off = align256(off + (size_t)B1 * 4);
    size_t o_col    = off; off = align256(off + (size_t)E * 4);
    size_t need = off;

    float*  dinv = (float*)((char*)d_ws + o_dinv);
    float*  tf   = (float*)((char*)d_ws + o_t);   // fallback f32 t
    __half* th   = (__half*)((char*)d_ws + o_t);  // main-path f16 t

    const int TB = 256;
    int gN = (N + TB - 1) / TB;
    int gE = (E + TB - 1) / TB;
    int ntiles = (N + TILE_R - 1) / TILE_R;

    if (ws_size >= need) {
        int* rowptr = (int*)((char*)d_ws + o_rowptr);
        int* cursor = (int*)((char*)d_ws + o_cursor);
        int* bsum   = (int*)((char*)d_ws + o_bsum);
        int* col    = (int*)((char*)d_ws + o_col);

        const bool vec4 = ((E & 3) == 0) && ((((uintptr_t)ei) & 15) == 0);
        const int E4 = E >> 2;
        int gE4 = (E4 + TB - 1) / TB;

        // pshift: dst>>pshift must land in [0, NPART)
        int pshift = 0;
        while (((N - 1) >> pshift) >= NPART) ++pshift;

        // CSR build
        hipMemsetAsync(cursor, 0, (size_t)N * 4, stream);
        if (vec4)
            cnt_count4_kernel<<<gE4, TB, 0, stream>>>((const int4*)dst, cursor, E4);
        else
            cnt_count_kernel<<<gE, TB, 0, stream>>>(dst, cursor, E);
        scan_reduce_kernel<<<B1, TB, 0, stream>>>(cursor, bsum, N);
        scan_bsum_kernel<<<1, 64, 0, stream>>>(bsum, B1, rowptr + N, E);
        scan_write_kernel<<<B1, TB, 0, stream>>>(cursor, bsum, rowptr, cursor, dinv, N);
        if (vec4)
            csr_fill_part4_kernel<<<gE4 * NPART, TB, 0, stream>>>((const int4*)src, (const int4*)dst,
                                                                  cursor, col, E4, pshift);
        else
            csr_fill_kernel<<<gE, TB, 0, stream>>>(src, dst, cursor, col, E);

        int gPull = (N + 15) / 16;
        // layer 1: t = f16((x @ W1) * dinv)
        gemm128_tiled<<<512, TB, 0, stream>>>(x, W1, nullptr, dinv, th, N, ntiles);
        agg_pull_h_kernel<<<gPull, TB, 0, stream>>>(th, rowptr, col, dinv, b1, out, N, 1);
        // layer 2
        gemm128_tiled<<<512, TB, 0, stream>>>(out, W2, nullptr, dinv, th, N, ntiles);
        agg_pull_h_kernel<<<gPull, TB, 0, stream>>>(th, rowptr, col, dinv, b2, out, N, 1);
        // layer 3+4 fused columns [Wmu|Wls]
        gemm128_tiled<<<512, TB, 0, stream>>>(out, Wmu, Wls, dinv, th, N, ntiles);
        agg_pull_final_h_kernel<<<gPull, TB, 0, stream>>>(th, rowptr, col, dinv, bmu, bls, out, N);
    } else {
        // fallback: atomic scatter path (f32)
        int gN32  = (N * 32 + TB - 1) / TB;
        int gE32h = (int)(((long long)E * 32 + TB - 1) / TB);
        deg_init_kernel<<<gN, TB, 0, stream>>>(dinv, N);
        deg_count_kernel<<<gE, TB, 0, stream>>>(dst, dinv, E);
        deg_rsqrt_kernel<<<gN, TB, 0, stream>>>(dinv, N);

        gemm128_kernel<<<2048, TB, 0, stream>>>(x, W1, nullptr, tf, N, 0);
        init_self_kernel<<<gN32, TB, 0, stream>>>((const float4*)tf, dinv, b1, (float4*)out, N);
        agg_edge_kernel<<<gE32h, TB, 0, stream>>>((const float4*)tf, src, dst, dinv, out, E);

        gemm128_kernel<<<2048, TB, 0, stream>>>(out, W2, nullptr, tf, N, 1);
        init_self_kernel<<<gN32, TB, 0, stream>>>((const float4*)tf, dinv, b2, (float4*)out, N);
        agg_edge_kernel<<<gE32h, TB, 0, stream>>>((const float4*)tf, src, dst, dinv, out, E);

        gemm128_kernel<<<2048, TB, 0, stream>>>(out, Wmu, Wls, tf, N, 1);
        init_final_kernel<<<gN32, TB, 0, stream>>>((const float4*)tf, dinv, bmu, bls, (float4*)out, N);
        agg_edge_final_kernel<<<gE32h, TB, 0, stream>>>((const float4*)tf, src, dst, dinv, out, N, E);
    }
}

// Round 14
// 532.751 us; speedup vs baseline: 1.6551x; 1.0049x over previous
//
#include <hip/hip_runtime.h>
#include <hip/hip_fp16.h>
#include <hip/hip_bf16.h>

// ---------------- small helpers ----------------
__device__ __forceinline__ float4 f4_fma(float4 a, float s, float4 acc) {
    acc.x = fmaf(a.x, s, acc.x); acc.y = fmaf(a.y, s, acc.y);
    acc.z = fmaf(a.z, s, acc.z); acc.w = fmaf(a.w, s, acc.w);
    return acc;
}

typedef const __attribute__((address_space(1))) unsigned int* gas_u32;
typedef __attribute__((address_space(3))) unsigned int* las_u32;

__device__ __forceinline__ void gl_lds16(const float* g, float* l) {
    __builtin_amdgcn_global_load_lds((gas_u32)(const void*)g, (las_u32)(void*)l, 16, 0, 0);
}

// f32x4 -> f16x4 packed store (8 B)
__device__ __forceinline__ void store_half4(__half* p, float4 v) {
    union { __half2 h[2]; uint2 u; } pk;
    pk.h[0] = __floats2half2_rn(v.x, v.y);
    pk.h[1] = __floats2half2_rn(v.z, v.w);
    *(uint2*)p = pk.u;
}

// 4 packed halves -> float4
__device__ __forceinline__ float4 h4_to_f4(uint2 r) {
    union { uint2 u; __half2 h[2]; } pk; pk.u = r;
    float2 a = __half22float2(pk.h[0]);
    float2 b = __half22float2(pk.h[1]);
    return make_float4(a.x, a.y, b.x, b.y);
}

// accumulate 8 halves (one uint4) into 8 f32 accumulators
__device__ __forceinline__ void acc_half8(float* acc, uint4 raw) {
    union { uint4 u; __half2 h[4]; } pk; pk.u = raw;
    float2 f0 = __half22float2(pk.h[0]);
    float2 f1 = __half22float2(pk.h[1]);
    float2 f2 = __half22float2(pk.h[2]);
    float2 f3 = __half22float2(pk.h[3]);
    acc[0] += f0.x; acc[1] += f0.y; acc[2] += f1.x; acc[3] += f1.y;
    acc[4] += f2.x; acc[5] += f2.y; acc[6] += f3.x; acc[7] += f3.y;
}

// ---------------- W conversion: f32 [128x128] (or [Wa|Wb] col-concat) -> f16 ----------------
__global__ __launch_bounds__(256) void convw_kernel(const float* __restrict__ Wa,
                                                    const float* __restrict__ Wb,
                                                    __half* __restrict__ o) {
    int i = blockIdx.x * 256 + threadIdx.x;  // 16384
    int k = i >> 7, j = i & 127;
    float w = Wb ? ((j < 64) ? Wa[k * 64 + j] : Wb[k * 64 + (j - 64)]) : Wa[i];
    o[i] = __float2half(w);
}

// ---------------- degree count ----------------
__global__ __launch_bounds__(256) void cnt_count4_kernel(const int4* __restrict__ dst4, int* cnt, int E4) {
    int i = blockIdx.x * blockDim.x + threadIdx.x;
    if (i < E4) {
        int4 d = dst4[i];
        atomicAdd(&cnt[d.x], 1);
        atomicAdd(&cnt[d.y], 1);
        atomicAdd(&cnt[d.z], 1);
        atomicAdd(&cnt[d.w], 1);
    }
}
__global__ __launch_bounds__(256) void cnt_count_kernel(const int* __restrict__ dst, int* cnt, int E) {
    int i = blockIdx.x * blockDim.x + threadIdx.x;
    if (i < E) atomicAdd(&cnt[dst[i]], 1);
}

// ---------------- exclusive scan (N ~ 100k) ----------------
#define SCAN_CHUNK 4096  // 256 threads * 16

__global__ __launch_bounds__(256) void scan_reduce_kernel(const int* __restrict__ cnt, int* bsum, int N) {
    __shared__ int sdata[256];
    int base = blockIdx.x * SCAN_CHUNK;
    int s = 0;
    for (int k = 0; k < 16; ++k) {
        int i = base + k * 256 + threadIdx.x;
        if (i < N) s += cnt[i];
    }
    sdata[threadIdx.x] = s;
    __syncthreads();
    for (int off = 128; off > 0; off >>= 1) {
        if (threadIdx.x < off) sdata[threadIdx.x] += sdata[threadIdx.x + off];
        __syncthreads();
    }
    if (threadIdx.x == 0) bsum[blockIdx.x] = sdata[0];
}

__global__ void scan_bsum_kernel(int* bsum, int B, int* rowptr_end, int E) {
    if (threadIdx.x == 0 && blockIdx.x == 0) {
        int run = 0;
        for (int i = 0; i < B; ++i) { int v = bsum[i]; bsum[i] = run; run += v; }
        *rowptr_end = E;  // rowptr[N] = E
    }
}

// emits rowptr, cursor (=rowptr copy), dinv
__global__ __launch_bounds__(256) void scan_write_kernel(const int* __restrict__ cnt,
                                                         const int* __restrict__ bsum,
                                                         int* rowptr, int* cursor,
                                                         float* dinv, int N) {
    __shared__ int sdata[256];
    int base = blockIdx.x * SCAN_CHUNK;
    int tbase = base + threadIdx.x * 16;
    int loc[16];
    int s = 0;
    for (int k = 0; k < 16; ++k) {
        int i = tbase + k;
        int v = (i < N) ? cnt[i] : 0;
        loc[k] = s; s += v;
    }
    sdata[threadIdx.x] = s;
    __syncthreads();
    for (int off = 1; off < 256; off <<= 1) {
        int v = sdata[threadIdx.x];
        int add = (threadIdx.x >= off) ? sdata[threadIdx.x - off] : 0;
        __syncthreads();
        sdata[threadIdx.x] = v + add;
        __syncthreads();
    }
    int texcl = (threadIdx.x == 0) ? 0 : sdata[threadIdx.x - 1];
    int boff = bsum[blockIdx.x];
    for (int k = 0; k < 16; ++k) {
        int i = tbase + k;
        if (i < N) {
            int rp = boff + texcl + loc[k];
            rowptr[i] = rp;
            cursor[i] = rp;
            dinv[i] = rsqrtf((float)(cnt[i] + 1));
        }
    }
}

// ---------------- XCD-partitioned csr fill (R12: 135 -> 71 us) ----------------
#define NPART 8

__global__ __launch_bounds__(256) void csr_fill_part4_kernel(const int4* __restrict__ src4,
                                                             const int4* __restrict__ dst4,
                                                             int* cursor, int* __restrict__ col,
                                                             int E4, int pshift) {
    int part = blockIdx.x & (NPART - 1);
    int i = (blockIdx.x >> 3) * blockDim.x + threadIdx.x;
    if (i >= E4) return;
    int4 s = src4[i];
    int4 d = dst4[i];
    if ((d.x >> pshift) == part) { int p = atomicAdd(&cursor[d.x], 1); col[p] = s.x; }
    if ((d.y >> pshift) == part) { int p = atomicAdd(&cursor[d.y], 1); col[p] = s.y; }
    if ((d.z >> pshift) == part) { int p = atomicAdd(&cursor[d.z], 1); col[p] = s.z; }
    if ((d.w >> pshift) == part) { int p = atomicAdd(&cursor[d.w], 1); col[p] = s.w; }
}

// non-vec4 fallback: direct fill
__global__ __launch_bounds__(256) void csr_fill_kernel(const int* __restrict__ src,
                                                       const int* __restrict__ dst,
                                                       int* cursor, int* __restrict__ col,
                                                       int E) {
    int e = blockIdx.x * blockDim.x + threadIdx.x;
    if (e >= E) return;
    int s = src[e], d = dst[e];
    int pos = atomicAdd(&cursor[d], 1);
    col[pos] = s;
}

// ---------------- register-tiled GEMM: t_h[N][128](f16) = (h[N][128](f32) @ Wh(f16)) * dinv[row] ----------------
// W pre-converted to f16 (32KB = exactly L1-sized; f32 W was 64KB > 32KB L1 ->
// inner-loop L2-latency stalls, VALUBusy 35%).
#define TILE_R 64

__global__ __launch_bounds__(256, 2) void gemm128_tiled(const float* __restrict__ h,
                                                        const __half* __restrict__ Wh,
                                                        const float* __restrict__ dinv,
                                                        __half* __restrict__ th,
                                                        int N, int ntiles) {
    __shared__ float hl[2][TILE_R * 128];

    const int lane = threadIdx.x & 63;
    const int wav  = threadIdx.x >> 6;
    const int jf4  = threadIdx.x & 31;
    const int rg   = threadIdx.x >> 5;

    const __half* wp = Wh + jf4 * 4;

    auto stage = [&](int buf, long long tile) {
        if (tile >= ntiles) return;
        long long row0 = tile * TILE_R;
        if (row0 + TILE_R <= N) {
            const float* gbase = h + row0 * 128 + (size_t)wav * (16 * 128) + lane * 4;
            float* lbase = &hl[buf][wav * (16 * 128)];
            #pragma unroll
            for (int m = 0; m < 8; ++m)
                gl_lds16(gbase + m * 256, lbase + m * 256);
        } else {
            for (int i = threadIdx.x; i < TILE_R * 32; i += 256) {
                int rl = i >> 5, k4 = i & 31;
                long long row = row0 + rl;
                float4 v = (row < N) ? ((const float4*)h)[row * 32 + k4]
                                     : make_float4(0.f, 0.f, 0.f, 0.f);
                *(float4*)&hl[buf][rl * 128 + k4 * 4] = v;
            }
        }
    };

    long long tile = blockIdx.x;
    stage(0, tile);
    __syncthreads();
    int cur = 0;

    for (; tile < ntiles; tile += gridDim.x) {
        stage(cur ^ 1, tile + gridDim.x);

        float4 acc[8];
        #pragma unroll
        for (int rr = 0; rr < 8; ++rr) acc[rr] = make_float4(0.f, 0.f, 0.f, 0.f);

        const float* hb = &hl[cur][rg * 8 * 128];
        #pragma unroll 4
        for (int k = 0; k < 128; k += 4) {
            float4 w0 = h4_to_f4(*(const uint2*)&wp[(size_t)(k + 0) * 128]);
            float4 w1 = h4_to_f4(*(const uint2*)&wp[(size_t)(k + 1) * 128]);
            float4 w2 = h4_to_f4(*(const uint2*)&wp[(size_t)(k + 2) * 128]);
            float4 w3 = h4_to_f4(*(const uint2*)&wp[(size_t)(k + 3) * 128]);
            #pragma unroll
            for (int rr = 0; rr < 8; ++rr) {
                float4 hv = *(const float4*)&hb[rr * 128 + k];
                acc[rr] = f4_fma(w0, hv.x, acc[rr]);
                acc[rr] = f4_fma(w1, hv.y, acc[rr]);
                acc[rr] = f4_fma(w2, hv.z, acc[rr]);
                acc[rr] = f4_fma(w3, hv.w, acc[rr]);
            }
        }

        long long row0 = tile * TILE_R;
        #pragma unroll
        for (int rr = 0; rr < 8; ++rr) {
            long long row = row0 + rg * 8 + rr;
            if (row < N) {
                float di = dinv[row];
                float4 r = acc[rr];
                r.x *= di; r.y *= di; r.z *= di; r.w *= di;
                store_half4(th + (size_t)row * 128 + jf4 * 4, r);
            }
        }
        __syncthreads();
        cur ^= 1;
    }
}

// ---------------- pull aggregation over f16 t ----------------
__global__ __launch_bounds__(256) void agg_pull_h_kernel(const __half* __restrict__ th,
                                                         const int* __restrict__ rowptr,
                                                         const int* __restrict__ col,
                                                         const float* __restrict__ dinv,
                                                         const float* __restrict__ b,
                                                         float* __restrict__ out,
                                                         int N, int relu) {
    int v = blockIdx.x * 16 + (threadIdx.x >> 4);
    int c = threadIdx.x & 15;   // 16B chunk (8 halves)
    if (v >= N) return;
    const uint4* tq = (const uint4*)th;  // row stride = 16 uint4
    int beg = rowptr[v], end = rowptr[v + 1];
    float a0[8] = {0,0,0,0,0,0,0,0}, a1[8] = {0,0,0,0,0,0,0,0};
    float a2[8] = {0,0,0,0,0,0,0,0}, a3[8] = {0,0,0,0,0,0,0,0};
    acc_half8(a0, tq[(size_t)v * 16 + c]);  // self-loop (pre-scaled)
    int e = beg;
    for (; e + 3 < end; e += 4) {
        int s0 = col[e], s1 = col[e + 1], s2 = col[e + 2], s3 = col[e + 3];
        uint4 r0 = tq[(size_t)s0 * 16 + c];
        uint4 r1 = tq[(size_t)s1 * 16 + c];
        uint4 r2 = tq[(size_t)s2 * 16 + c];
        uint4 r3 = tq[(size_t)s3 * 16 + c];
        acc_half8(a0, r0); acc_half8(a1, r1); acc_half8(a2, r2); acc_half8(a3, r3);
    }
    for (; e < end; ++e) acc_half8(a0, tq[(size_t)col[e] * 16 + c]);
    float di = dinv[v];
    float4 b0 = *(const float4*)(b + c * 8);
    float4 b1v = *(const float4*)(b + c * 8 + 4);
    float o[8];
    #pragma unroll
    for (int i = 0; i < 8; ++i) {
        float bb = (i < 4) ? (&b0.x)[i] : (&b1v.x)[i - 4];
        float s = (a0[i] + a1[i]) + (a2[i] + a3[i]);
        o[i] = fmaf(s, di, bb);
        if (relu) o[i] = fmaxf(o[i], 0.f);
    }
    float4* op = (float4*)(out + (size_t)v * 128 + c * 8);
    op[0] = make_float4(o[0], o[1], o[2], o[3]);
    op[1] = make_float4(o[4], o[5], o[6], o[7]);
}

// final: lane chunks c<8 -> mu, c>=8 -> logstd (split output)
__global__ __launch_bounds__(256) void agg_pull_final_h_kernel(const __half* __restrict__ th,
                                                               const int* __restrict__ rowptr,
                                                               const int* __restrict__ col,
                                                               const float* __restrict__ dinv,
                                                               const float* __restrict__ bmu,
                                                               const float* __restrict__ bls,
                                                               float* __restrict__ out,
                                                               int N) {
    int v = blockIdx.x * 16 + (threadIdx.x >> 4);
    int c = threadIdx.x & 15;
    if (v >= N) return;
    const uint4* tq = (const uint4*)th;
    int beg = rowptr[v], end = rowptr[v + 1];
    float a0[8] = {0,0,0,0,0,0,0,0}, a1[8] = {0,0,0,0,0,0,0,0};
    float a2[8] = {0,0,0,0,0,0,0,0}, a3[8] = {0,0,0,0,0,0,0,0};
    acc_half8(a0, tq[(size_t)v * 16 + c]);
    int e = beg;
    for (; e + 3 < end; e += 4) {
        int s0 = col[e], s1 = col[e + 1], s2 = col[e + 2], s3 = col[e + 3];
        uint4 r0 = tq[(size_t)s0 * 16 + c];
        uint4 r1 = tq[(size_t)s1 * 16 + c];
        uint4 r2 = tq[(size_t)s2 * 16 + c];
        uint4 r3 = tq[(size_t)s3 * 16 + c];
        acc_half8(a0, r0); acc_half8(a1, r1); acc_half8(a2, r2); acc_half8(a3, r3);
    }
    for (; e < end; ++e) acc_half8(a0, tq[(size_t)col[e] * 16 + c]);
    float di = dinv[v];
    const float* bp = (c < 8) ? (bmu + c * 8) : (bls + (c - 8) * 8);
    float* obase = (c < 8) ? (out + (size_t)v * 64 + c * 8)
                           : (out + (size_t)N * 64 + (size_t)v * 64 + (size_t)(c - 8) * 8);
    float4 b0 = *(const float4*)bp;
    float4 b1v = *(const float4*)(bp + 4);
    float o[8];
    #pragma unroll
    for (int i = 0; i < 8; ++i) {
        float bb = (i < 4) ? (&b0.x)[i] : (&b1v.x)[i - 4];
        float s = (a0[i] + a1[i]) + (a2[i] + a3[i]);
        o[i] = fmaf(s, di, bb);
    }
    ((float4*)obase)[0] = make_float4(o[0], o[1], o[2], o[3]);
    ((float4*)obase)[1] = make_float4(o[4], o[5], o[6], o[7]);
}

// ---------------- fallback (atomic scatter, f32) kernels ----------------
__global__ __launch_bounds__(256) void deg_init_kernel(float* deg, int N) {
    int i = blockIdx.x * blockDim.x + threadIdx.x;
    if (i < N) deg[i] = 1.0f;
}
__global__ __launch_bounds__(256) void deg_count_kernel(const int* __restrict__ dst, float* deg, int E) {
    int i = blockIdx.x * blockDim.x + threadIdx.x;
    if (i < E) unsafeAtomicAdd(&deg[dst[i]], 1.0f);
}
__global__ __launch_bounds__(256) void deg_rsqrt_kernel(float* deg, int N) {
    int i = blockIdx.x * blockDim.x + threadIdx.x;
    if (i < N) deg[i] = rsqrtf(deg[i]);
}
__global__ __launch_bounds__(256) void gemm128_kernel(const float* __restrict__ h,
                                                      const float* __restrict__ Wa,
                                                      const float* __restrict__ Wb,
                                                      float* __restrict__ t,
                                                      int N, int relu) {
    __shared__ float Wl[128 * 128];
    __shared__ float hl[2][128];
    for (int i = threadIdx.x; i < 128 * 128; i += 256) {
        int k = i >> 7, j = i & 127;
        float w;
        if (Wb) w = (j < 64) ? Wa[k * 64 + j] : Wb[k * 64 + (j - 64)];
        else    w = Wa[i];
        Wl[i] = w;
    }
    __syncthreads();
    int col = threadIdx.x & 127;
    int r   = threadIdx.x >> 7;
    for (long long pair = blockIdx.x; pair * 2 < N; pair += gridDim.x) {
        int row0 = (int)(pair * 2);
        {
            int rr = threadIdx.x >> 7, k = threadIdx.x & 127;
            int row = row0 + rr;
            float v = (row < N) ? h[(size_t)row * 128 + k] : 0.0f;
            if (relu) v = fmaxf(v, 0.0f);
            hl[rr][k] = v;
        }
        __syncthreads();
        float acc = 0.0f;
        #pragma unroll
        for (int k = 0; k < 128; k += 4) {
            float4 hv = *(const float4*)&hl[r][k];
            acc += hv.x * Wl[(k + 0) * 128 + col];
            acc += hv.y * Wl[(k + 1) * 128 + col];
            acc += hv.z * Wl[(k + 2) * 128 + col];
            acc += hv.w * Wl[(k + 3) * 128 + col];
        }
        int row = row0 + r;
        if (row < N) t[(size_t)row * 128 + col] = acc;
        __syncthreads();
    }
}
__global__ __launch_bounds__(256) void init_self_kernel(const float4* __restrict__ t4,
                                                        const float* __restrict__ dinv,
                                                        const float* __restrict__ b,
                                                        float4* __restrict__ out, int N) {
    int idx = blockIdx.x * blockDim.x + threadIdx.x;
    int v = idx >> 5, c = idx & 31;
    if (v >= N) return;
    float di = dinv[v];
    float s = di * di;
    float4 x = t4[(size_t)v * 32 + c];
    float4 bb = ((const float4*)b)[c];
    out[(size_t)v * 32 + c] = make_float4(fmaf(x.x, s, bb.x), fmaf(x.y, s, bb.y),
                                          fmaf(x.z, s, bb.z), fmaf(x.w, s, bb.w));
}
__global__ __launch_bounds__(256) void init_final_kernel(const float4* __restrict__ t4,
                                                         const float* __restrict__ dinv,
                                                         const float* __restrict__ bmu,
                                                         const float* __restrict__ bls,
                                                         float4* __restrict__ out4, int N) {
    int idx = blockIdx.x * blockDim.x + threadIdx.x;
    int v = idx >> 5, c = idx & 31;
    if (v >= N) return;
    int half = c >> 4, cc = c & 15;
    float di = dinv[v];
    float s = di * di;
    float4 x = t4[(size_t)v * 32 + c];
    float4 bb = half ? ((const float4*)bls)[cc] : ((const float4*)bmu)[cc];
    out4[(size_t)half * N * 16 + (size_t)v * 16 + cc] =
        make_float4(fmaf(x.x, s, bb.x), fmaf(x.y, s, bb.y),
                    fmaf(x.z, s, bb.z), fmaf(x.w, s, bb.w));
}
__global__ __launch_bounds__(256) void agg_edge_kernel(const float4* __restrict__ t4,
                                                       const int* __restrict__ src,
                                                       const int* __restrict__ dst,
                                                       const float* __restrict__ dinv,
                                                       float* __restrict__ out, int E) {
    int idx = blockIdx.x * blockDim.x + threadIdx.x;
    int e = idx >> 5, c = idx & 31;
    if (e >= E) return;
    int s = src[e], d = dst[e];
    float w = dinv[s] * dinv[d];
    float4 v = t4[(size_t)s * 32 + c];
    float* o = out + (size_t)d * 128 + c * 4;
    unsafeAtomicAdd(o + 0, v.x * w);
    unsafeAtomicAdd(o + 1, v.y * w);
    unsafeAtomicAdd(o + 2, v.z * w);
    unsafeAtomicAdd(o + 3, v.w * w);
}
__global__ __launch_bounds__(256) void agg_edge_final_kernel(const float4* __restrict__ t4,
                                                             const int* __restrict__ src,
                                                             const int* __restrict__ dst,
                                                             const float* __restrict__ dinv,
                                                             float* __restrict__ out, int N, int E) {
    int idx = blockIdx.x * blockDim.x + threadIdx.x;
    int e = idx >> 5, c = idx & 31;
    if (e >= E) return;
    int s = src[e], d = dst[e];
    int half = c >> 4, cc = c & 15;
    float w = dinv[s] * dinv[d];
    float4 v = t4[(size_t)s * 32 + c];
    float* o = out + (size_t)half * N * 64 + (size_t)d * 64 + cc * 4;
    unsafeAtomicAdd(o + 0, v.x * w);
    unsafeAtomicAdd(o + 1, v.y * w);
    unsafeAtomicAdd(o + 2, v.z * w);
    unsafeAtomicAdd(o + 3, v.w * w);
}

// ---------------- launch ----------------
extern "C" void kernel_launch(void* const* d_in, const int* in_sizes, int n_in,
                              void* d_out, int out_size, void* d_ws, size_t ws_size,
                              hipStream_t stream) {
    const float* x   = (const float*)d_in[0];
    const int*   ei  = (const int*)d_in[1];
    const float* W1  = (const float*)d_in[2];
    const float* b1  = (const float*)d_in[3];
    const float* W2  = (const float*)d_in[4];
    const float* b2  = (const float*)d_in[5];
    const float* Wmu = (const float*)d_in[6];
    const float* bmu = (const float*)d_in[7];
    const float* Wls = (const float*)d_in[8];
    const float* bls = (const float*)d_in[9];

    const int N = in_sizes[0] / 128;
    const int E = in_sizes[1] / 2;
    const int* src = ei;
    const int* dst = ei + E;

    float* out = (float*)d_out;  // f32 h buffer for hidden layers, final mu|ls

    auto align256 = [](size_t o) { return (o + 255) & ~(size_t)255; };
    const int B1 = (N + SCAN_CHUNK - 1) / SCAN_CHUNK;

    size_t off = 0;
    size_t o_dinv   = off; off = align256(off + (size_t)N * 4);
    size_t o_t      = off; off = align256(off + (size_t)N * 128 * 4);  // f32 for fallback; f16 path uses half
    size_t o_rowptr = off; off = align256(off + (size_t)(N + 1) * 4);
    size_t o_cursor = off; off = align256(off + (size_t)N * 4);        // also cnt
    size_t o_bsum   = off; off = align256(off + (size_t)B1 * 4);
    size_t o_col    = off; off = align256(off + (size_t)E * 4);
    size_t o_wh     = off; off = align256(off + (size_t)3 * 128 * 128 * 2);  // 3x f16 W
    size_t need = off;

    float*  dinv = (float*)((char*)d_ws + o_dinv);
    float*  tf   = (float*)((char*)d_ws + o_t);   // fallback f32 t
    __half* th   = (__half*)((char*)d_ws + o_t);  // main-path f16 t

    const int TB = 256;
    int gN = (N + TB - 1) / TB;
    int gE = (E + TB - 1) / TB;
    int ntiles = (N + TILE_R - 1) / TILE_R;

    if (ws_size >= need) {
        int* rowptr = (int*)((char*)d_ws + o_rowptr);
        int* cursor = (int*)((char*)d_ws + o_cursor);
        int* bsum   = (int*)((char*)d_ws + o_bsum);
        int* col    = (int*)((char*)d_ws + o_col);
        __half* wh1 = (__half*)((char*)d_ws + o_wh);
        __half* wh2 = wh1 + 128 * 128;
        __half* wh3 = wh2 + 128 * 128;

        const bool vec4 = ((E & 3) == 0) && ((((uintptr_t)ei) & 15) == 0);
        const int E4 = E >> 2;
        int gE4 = (E4 + TB - 1) / TB;

        int pshift = 0;
        while (((N - 1) >> pshift) >= NPART) ++pshift;

        // W conversion (f16, L1-resident in gemm)
        convw_kernel<<<64, TB, 0, stream>>>(W1, nullptr, wh1);
        convw_kernel<<<64, TB, 0, stream>>>(W2, nullptr, wh2);
        convw_kernel<<<64, TB, 0, stream>>>(Wmu, Wls, wh3);

        // CSR build
        hipMemsetAsync(cursor, 0, (size_t)N * 4, stream);
        if (vec4)
            cnt_count4_kernel<<<gE4, TB, 0, stream>>>((const int4*)dst, cursor, E4);
        else
            cnt_count_kernel<<<gE, TB, 0, stream>>>(dst, cursor, E);
        scan_reduce_kernel<<<B1, TB, 0, stream>>>(cursor, bsum, N);
        scan_bsum_kernel<<<1, 64, 0, stream>>>(bsum, B1, rowptr + N, E);
        scan_write_kernel<<<B1, TB, 0, stream>>>(cursor, bsum, rowptr, cursor, dinv, N);
        if (vec4)
            csr_fill_part4_kernel<<<gE4 * NPART, TB, 0, stream>>>((const int4*)src, (const int4*)dst,
                                                                  cursor, col, E4, pshift);
        else
            csr_fill_kernel<<<gE, TB, 0, stream>>>(src, dst, cursor, col, E);

        int gPull = (N + 15) / 16;
        // layer 1: t = f16((x @ W1) * dinv)
        gemm128_tiled<<<512, TB, 0, stream>>>(x, wh1, dinv, th, N, ntiles);
        agg_pull_h_kernel<<<gPull, TB, 0, stream>>>(th, rowptr, col, dinv, b1, out, N, 1);
        // layer 2
        gemm128_tiled<<<512, TB, 0, stream>>>(out, wh2, dinv, th, N, ntiles);
        agg_pull_h_kernel<<<gPull, TB, 0, stream>>>(th, rowptr, col, dinv, b2, out, N, 1);
        // layer 3+4 fused columns [Wmu|Wls]
        gemm128_tiled<<<512, TB, 0, stream>>>(out, wh3, dinv, th, N, ntiles);
        agg_pull_final_h_kernel<<<gPull, TB, 0, stream>>>(th, rowptr, col, dinv, bmu, bls, out, N);
    } else {
        // fallback: atomic scatter path (f32)
        int gN32  = (N * 32 + TB - 1) / TB;
        int gE32h = (int)(((long long)E * 32 + TB - 1) / TB);
        deg_init_kernel<<<gN, TB, 0, stream>>>(dinv, N);
        deg_count_kernel<<<gE, TB, 0, stream>>>(dst, dinv, E);
        deg_rsqrt_kernel<<<gN, TB, 0, stream>>>(dinv, N);

        gemm128_kernel<<<2048, TB, 0, stream>>>(x, W1, nullptr, tf, N, 0);
        init_self_kernel<<<gN32, TB, 0, stream>>>((const float4*)tf, dinv, b1, (float4*)out, N);
        agg_edge_kernel<<<gE32h, TB, 0, stream>>>((const float4*)tf, src, dst, dinv, out, E);

        gemm128_kernel<<<2048, TB, 0, stream>>>(out, W2, nullptr, tf, N, 1);
        init_self_kernel<<<gN32, TB, 0, stream>>>((const float4*)tf, dinv, b2, (float4*)out, N);
        agg_edge_kernel<<<gE32h, TB, 0, stream>>>((const float4*)tf, src, dst, dinv, out, E);

        gemm128_kernel<<<2048, TB, 0, stream>>>(out, Wmu, Wls, tf, N, 1);
        init_final_kernel<<<gN32, TB, 0, stream>>>((const float4*)tf, dinv, bmu, bls, (float4*)out, N);
        agg_edge_final_kernel<<<gE32h, TB, 0, stream>>>((const float4*)tf, src, dst, dinv, out, N, E);
    }
}